// Round 14
// baseline (186.683 us; speedup 1.0000x reference)
//
#include <hip/hip_runtime.h>
#include <hip/hip_bf16.h>
#include <cstdint>
#include <cstddef>

// Problem constants
#define T_DIM 2048
#define B_DIM 2
#define E_DIM 1024
#define H_DIM 16
#define HD_DIM 64
#define M_ROWS 4096   // T*B
#define BH_DIM 32     // B*H

typedef __attribute__((ext_vector_type(8))) short bf16x8;
typedef __attribute__((ext_vector_type(4))) float f32x4;

__device__ __forceinline__ short f2bf(float x) {
  unsigned u = __float_as_uint(x);
  u += 0x7fffu + ((u >> 16) & 1u);
  return (short)(u >> 16);
}

__device__ __forceinline__ float exp2_hw(float x) {
  return __builtin_amdgcn_exp2f(x);  // v_exp_f32: D = 2^S0
}

__device__ __forceinline__ f32x4 mfma_bf16(bf16x8 a, bf16x8 b, f32x4 c) {
  return __builtin_amdgcn_mfma_f32_16x16x32_bf16(a, b, c, 0, 0, 0);
}

__device__ __forceinline__ unsigned cvt_pk_bf16(float lo, float hi) {
  unsigned r;
  asm volatile("v_cvt_pk_bf16_f32 %0, %1, %2" : "=v"(r) : "v"(lo), "v"(hi));
  return r;
}

__device__ __forceinline__ void gload_lds16(const void* g, void* l) {
  __builtin_amdgcn_global_load_lds(
      (const __attribute__((address_space(1))) void*)g,
      (__attribute__((address_space(3))) void*)l,
      16, 0, 0);
}

// ---------------------------------------------------------------------------
// Fused f32 -> bf16 conversion: one launch covers q/k/v/in_proj_w/out_w.
// ---------------------------------------------------------------------------
__global__ __launch_bounds__(256) void cvt_all_kernel(
    const float* __restrict__ q, const float* __restrict__ k,
    const float* __restrict__ v, const float* __restrict__ w_in,
    const float* __restrict__ w_out, short* __restrict__ Xb,
    short* __restrict__ Wb) {
  int bid = blockIdx.x;
  const float* src;
  short* dst;
  int base;
  if (bid < 4096) {
    src = q; dst = Xb; base = bid;
  } else if (bid < 8192) {
    src = k; dst = Xb + 4194304; base = bid - 4096;
  } else if (bid < 12288) {
    src = v; dst = Xb + 8388608; base = bid - 8192;
  } else if (bid < 15360) {
    src = w_in; dst = Wb; base = bid - 12288;
  } else {
    src = w_out; dst = Wb + 3145728; base = bid - 15360;
  }
  int i = base * 256 + threadIdx.x;
  float4 vv = ((const float4*)src)[i];
  short4 o;
  o.x = f2bf(vv.x); o.y = f2bf(vv.y); o.z = f2bf(vv.z); o.w = f2bf(vv.w);
  ((short4*)dst)[i] = o;
}

// ---------------------------------------------------------------------------
// Projection GEMM v2: BK=64 (half the barrier pairs of BK=32), 128x128 tile,
// 256 threads (4 waves 2x2), global_load_lds staging into XOR-swizzled
// 128x64 LDS slabs (flash's proven slot scheme: LDS[row][d]=glob[row][d^(row&7)]).
// XCD-chunked tile swizzle. mode 0: q (scaled log2e/8) / 1: k / 2: v (transp)
// / 3: out (f32).
// ---------------------------------------------------------------------------
__global__ __launch_bounds__(256) void proj_gemm_kernel(
    const short* __restrict__ A0, const short* __restrict__ W0,
    const float* __restrict__ b0,
    short* __restrict__ q_s, short* __restrict__ k_s, short* __restrict__ vT,
    float* __restrict__ outf, int mode_in) {
  int mode = (mode_in < 0) ? (int)blockIdx.z : mode_in;
  const short* A = (mode_in < 0) ? A0 + (size_t)mode * (size_t)M_ROWS * 1024 : A0;
  const short* W = W0 + (size_t)mode * 1024 * 1024;
  const float* bias = (mode_in < 0) ? b0 + mode * 1024 : b0;

  __shared__ short As[128 * 64];   // 16 KiB, XOR-swizzled slots
  __shared__ short Bs[128 * 64];

  int tid = threadIdx.x;
  int lane = tid & 63;
  int wave = tid >> 6;
  int wm = wave >> 1, wn = wave & 1;
  int g = lane >> 4;
  int l7 = lane & 7;
  // XCD-chunked swizzle: HW dispatch id h -> logical tile l so each XCD
  // (h%8) gets 32 consecutive logical tiles (4 brow-panels x 8 bcols).
  int hwid = blockIdx.y * 8 + blockIdx.x;  // 0..255
  int l = (hwid & 7) * 32 + (hwid >> 3);   // bijective
  int brow = (l >> 3) * 128;
  int bcol = (l & 7) * 128;

  f32x4 acc[4][4];
#pragma unroll
  for (int i = 0; i < 4; i++)
#pragma unroll
    for (int j = 0; j < 4; j++) acc[i][j] = (f32x4){0.f, 0.f, 0.f, 0.f};

  for (int k0 = 0; k0 < 1024; k0 += 64) {
#pragma unroll
    for (int j = 0; j < 4; j++) {
      int chunk = wave * 4 + j;            // 0..15, 8 rows each
      int row = chunk * 8 + (lane >> 3);   // tile row this lane fetches
      int sx = l7 ^ (row & 7);             // pre-swizzled source slot (16B)
      gload_lds16(A + (size_t)(brow + row) * 1024 + k0 + sx * 8, &As[chunk * 512]);
      gload_lds16(W + (size_t)(bcol + row) * 1024 + k0 + sx * 8, &Bs[chunk * 512]);
    }
    __syncthreads();

#pragma unroll
    for (int half = 0; half < 2; ++half) {
      bf16x8 af[4], bf_[4];
#pragma unroll
      for (int mi = 0; mi < 4; mi++) {
        int row = wm * 64 + mi * 16 + (lane & 15);
        af[mi] = *(const bf16x8*)&As[row * 64 + ((half * 4 + g) ^ (lane & 7)) * 8];
      }
#pragma unroll
      for (int ni = 0; ni < 4; ni++) {
        int row = wn * 64 + ni * 16 + (lane & 15);
        bf_[ni] = *(const bf16x8*)&Bs[row * 64 + ((half * 4 + g) ^ (lane & 7)) * 8];
      }
#pragma unroll
      for (int mi = 0; mi < 4; mi++)
#pragma unroll
        for (int ni = 0; ni < 4; ni++)
          acc[mi][ni] = mfma_bf16(af[mi], bf_[ni], acc[mi][ni]);
    }
    __syncthreads();
  }

#pragma unroll
  for (int mi = 0; mi < 4; mi++) {
#pragma unroll
    for (int ni = 0; ni < 4; ni++) {
      int col = bcol + wn * 64 + ni * 16 + (lane & 15);
      float bv = bias[col];
      int row0 = brow + wm * 64 + mi * 16 + (lane >> 4) * 4;
#pragma unroll
      for (int r = 0; r < 4; r++) {
        int row = row0 + r;
        float val = acc[mi][ni][r] + bv;
        int t = row >> 1, b = row & 1;
        int h = col >> 6, hd = col & 63;
        if (mode == 0) {
          // 0.125 (1/sqrt(HD)) * log2(e): scores become log2-domain
          q_s[((size_t)((b << 4) + h) * T_DIM + t) * HD_DIM + hd] =
              f2bf(val * 0.1803368801f);
        } else if (mode == 1) {
          k_s[((size_t)((b << 4) + h) * T_DIM + t) * HD_DIM + hd] = f2bf(val);
        } else if (mode == 2) {
          vT[((size_t)((b << 4) + h) * HD_DIM + hd) * T_DIM + t] = f2bf(val);
        } else {
          outf[(size_t)row * 1024 + col] = val;
        }
      }
    }
  }
}

// ---------------------------------------------------------------------------
// Flash attention v5 + XCD-chunked block swizzle (proven, 59.1us; FETCH 12MB).
// Swapped QK^T, packed b64 P writes, 32 t/wave, counted-vmcnt two-barrier
// pipeline, exp2 domain. Writes AO (bf16) and c[bh][t] = -log2(l).
// ---------------------------------------------------------------------------
__device__ __forceinline__ void stage_kv(const short* kb, const short* vb, int s0,
                                         short* Ktb, short* Vtb, int tid) {
  int r0 = tid >> 3;                 // row 0..31 (issue 0) / +32 (issue 1)
  int sx = (tid & 7) ^ (r0 & 7);     // pre-swizzled source slot (16B units)
  gload_lds16(kb + (size_t)(s0 + r0) * 64 + sx * 8, Ktb + tid * 8);
  gload_lds16(kb + (size_t)(s0 + 32 + r0) * 64 + sx * 8, Ktb + 2048 + tid * 8);
  gload_lds16(vb + (size_t)r0 * T_DIM + s0 + sx * 8, Vtb + tid * 8);
  gload_lds16(vb + (size_t)(32 + r0) * T_DIM + s0 + sx * 8, Vtb + 2048 + tid * 8);
}

__global__ __launch_bounds__(256) void flash_fwd_kernel(
    const short* __restrict__ q_s, const short* __restrict__ k_s,
    const short* __restrict__ vT, short* __restrict__ AO,
    float* __restrict__ c_ws) {
  int tid = threadIdx.x;
  int lane = tid & 63;
  int wave = tid >> 6;
  // XCD-chunked swizzle: 512 blocks, XCD = hw%8 owns 64 logical blocks
  // = 4 complete bh groups of 16 t-blocks (bijective).
  int lin = blockIdx.y * 16 + blockIdx.x;  // 0..511
  int L = (lin & 7) * 64 + (lin >> 3);
  int bh = L >> 4;
  int t0w = (L & 15) * 128 + wave * 32;    // wave owns 32 t rows
  int tp = lane & 15;
  int g = lane >> 4;
  int sw = tp & 7;

  const short* qb = q_s + (size_t)bh * T_DIM * HD_DIM;
  const short* kb = k_s + (size_t)bh * T_DIM * HD_DIM;
  const short* vb = vT + (size_t)bh * HD_DIM * T_DIM;

  __shared__ short Kt[2][64 * 64];     // [s][hd], XOR-swizzled slots
  __shared__ short Vt[2][64 * 64];     // [hd][s], XOR-swizzled slots
  __shared__ short Pt[4][2][16 * 72];  // per-wave, per-half P; row stride 72

  // B-operand Q fragments for both 16-row halves
  bf16x8 qfA0 = *(const bf16x8*)&qb[(t0w + tp) * HD_DIM + g * 8];
  bf16x8 qfA1 = *(const bf16x8*)&qb[(t0w + tp) * HD_DIM + 32 + g * 8];
  bf16x8 qfB0 = *(const bf16x8*)&qb[(t0w + 16 + tp) * HD_DIM + g * 8];
  bf16x8 qfB1 = *(const bf16x8*)&qb[(t0w + 16 + tp) * HD_DIM + 32 + g * 8];

  f32x4 accA[4], accB[4];
#pragma unroll
  for (int i = 0; i < 4; i++) {
    accA[i] = (f32x4){0.f, 0.f, 0.f, 0.f};
    accB[i] = (f32x4){0.f, 0.f, 0.f, 0.f};
  }
  float lA = 0.f, lB = 0.f;

  short* PA = Pt[wave][0];
  short* PB = Pt[wave][1];

  stage_kv(kb, vb, 0, Kt[0], Vt[0], tid);

#pragma unroll 1
  for (int i = 0; i < 32; ++i) {
    int cur = i & 1;
    // barrier 1: all waves done READING buf[cur^1] (iter i-1) -> safe to overwrite
    __builtin_amdgcn_s_barrier();
    if (i + 1 < 32) {
      stage_kv(kb, vb, (i + 1) * 64, Kt[cur ^ 1], Vt[cur ^ 1], tid);
      asm volatile("s_waitcnt vmcnt(4)" ::: "memory");  // stage(i) retired
    } else {
      asm volatile("s_waitcnt vmcnt(0)" ::: "memory");  // tail: drain
    }
    // barrier 2: every wave's stage(i) complete -> buf[cur] readable
    __builtin_amdgcn_s_barrier();
    __builtin_amdgcn_sched_barrier(0);
    const short* Kc = Kt[cur];
    const short* Vc = Vt[cur];

    // QK^T (swapped: A=K rows s, B=Q rows t) + softmax-numerator + packed P
#pragma unroll
    for (int sn = 0; sn < 4; ++sn) {
      int row = sn * 16 + tp;
      bf16x8 kf0 = *(const bf16x8*)&Kc[row * 64 + (g ^ sw) * 8];
      bf16x8 kf1 = *(const bf16x8*)&Kc[row * 64 + ((g | 4) ^ sw) * 8];
      f32x4 zA = (f32x4){0.f, 0.f, 0.f, 0.f};
      zA = mfma_bf16(kf0, qfA0, zA);
      zA = mfma_bf16(kf1, qfA1, zA);
      f32x4 zB = (f32x4){0.f, 0.f, 0.f, 0.f};
      zB = mfma_bf16(kf0, qfB0, zB);
      zB = mfma_bf16(kf1, qfB1, zB);
      float a0 = exp2_hw(zA[0]), a1 = exp2_hw(zA[1]);
      float a2 = exp2_hw(zA[2]), a3 = exp2_hw(zA[3]);
      float b0 = exp2_hw(zB[0]), b1 = exp2_hw(zB[1]);
      float b2 = exp2_hw(zB[2]), b3 = exp2_hw(zB[3]);
      lA += (a0 + a1) + (a2 + a3);
      lB += (b0 + b1) + (b2 + b3);
      uint2 wa, wb;
      wa.x = cvt_pk_bf16(a0, a1); wa.y = cvt_pk_bf16(a2, a3);
      wb.x = cvt_pk_bf16(b0, b1); wb.y = cvt_pk_bf16(b2, b3);
      *(uint2*)&PA[tp * 72 + sn * 16 + g * 4] = wa;  // s = sn*16 + g*4 + 0..3
      *(uint2*)&PB[tp * 72 + sn * 16 + g * 4] = wb;
    }

    // PV: A = P rows t, B = V^T rows hd (V fragments shared across halves)
#pragma unroll
    for (int c32 = 0; c32 < 2; ++c32) {
      bf16x8 pfA = *(const bf16x8*)&PA[tp * 72 + c32 * 32 + g * 8];
      bf16x8 pfB = *(const bf16x8*)&PB[tp * 72 + c32 * 32 + g * 8];
#pragma unroll
      for (int hdt = 0; hdt < 4; ++hdt) {
        bf16x8 vf = *(const bf16x8*)&Vc[(hdt * 16 + tp) * 64 + ((c32 * 4 + g) ^ sw) * 8];
        accA[hdt] = mfma_bf16(pfA, vf, accA[hdt]);
        accB[hdt] = mfma_bf16(pfB, vf, accB[hdt]);
      }
    }
  }

  // epilogue: reduce l per t-row (lane's l is for t-row tp of its half)
  lA += __shfl_xor(lA, 16); lA += __shfl_xor(lA, 32);
  lB += __shfl_xor(lB, 16); lB += __shfl_xor(lB, 32);
  float liA[4], liB[4];
#pragma unroll
  for (int r = 0; r < 4; r++) {
    liA[r] = 1.0f / __shfl(lA, g * 4 + r);
    liB[r] = 1.0f / __shfl(lB, g * 4 + r);
  }
  int b = bh >> 4, h = bh & 15;
#pragma unroll
  for (int hdt = 0; hdt < 4; hdt++) {
#pragma unroll
    for (int r = 0; r < 4; r++) {
      int tA = t0w + g * 4 + r;
      int tB = t0w + 16 + g * 4 + r;
      AO[(size_t)(tA * 2 + b) * E_DIM + h * 64 + hdt * 16 + tp] =
          f2bf(accA[hdt][r] * liA[r]);
      AO[(size_t)(tB * 2 + b) * E_DIM + h * 64 + hdt * 16 + tp] =
          f2bf(accB[hdt][r] * liB[r]);
    }
  }
  if (lane < 16) {
    c_ws[bh * T_DIM + t0w + tp] = -__log2f(lA);
    c_ws[bh * T_DIM + t0w + 16 + tp] = -__log2f(lB);
  }
}

// ---------------------------------------------------------------------------
// attn_weights v3: out[b,t,s] = (1/H) * sum_h exp2(score[bh,t,s] + c[bh,t])
// Block 128t x 64s, 4 waves x 32 t-rows; per head stage Q(128x64)+K(64x64)
// (dbuf, XOR-swizzled source), counted-vmcnt two-barrier pipeline.
// ---------------------------------------------------------------------------
__device__ __forceinline__ void stage_qk(const short* qh, const short* kh,
                                         int tbase, int sbase,
                                         short* Qb, short* Kb, int tid) {
  int r0 = tid >> 3;                 // row 0..31
  int sx = (tid & 7) ^ (r0 & 7);     // pre-swizzled source slot (16B units)
#pragma unroll
  for (int c = 0; c < 4; ++c)        // Q: 128 rows, 4 chunks of 32
    gload_lds16(qh + (size_t)(tbase + c * 32 + r0) * 64 + sx * 8,
                Qb + c * 2048 + tid * 8);
  gload_lds16(kh + (size_t)(sbase + r0) * 64 + sx * 8, Kb + tid * 8);
  gload_lds16(kh + (size_t)(sbase + 32 + r0) * 64 + sx * 8, Kb + 2048 + tid * 8);
}

__global__ __launch_bounds__(256) void attn_weights_kernel(
    const short* __restrict__ q_s, const short* __restrict__ k_s,
    const float* __restrict__ c_ws, float* __restrict__ wout) {
  int b = blockIdx.z;
  int tid = threadIdx.x;
  int lane = tid & 63;
  int wave = tid >> 6;
  int tbase = blockIdx.y * 128;
  int sbase = blockIdx.x * 64;
  int tp = lane & 15;
  int g = lane >> 4;
  int tw = wave * 32;                 // wave's local t-row base (32 rows)
  int tqA = tbase + tw + g * 4;       // accumulator t bases
  int tqB = tqA + 16;
  int sw = tp & 7;

  __shared__ short Qt[2][128 * 64];
  __shared__ short Kt[2][64 * 64];

  float wsA[4][4], wsB[4][4];
#pragma unroll
  for (int st = 0; st < 4; st++)
#pragma unroll
    for (int r = 0; r < 4; r++) { wsA[st][r] = 0.f; wsB[st][r] = 0.f; }

  const size_t hstride = (size_t)T_DIM * HD_DIM;
  const short* qh0 = q_s + (size_t)(b * 16) * hstride;
  const short* kh0 = k_s + (size_t)(b * 16) * hstride;

  stage_qk(qh0, kh0, tbase, sbase, Qt[0], Kt[0], tid);

#pragma unroll 1
  for (int h = 0; h < 16; ++h) {
    int bh = b * 16 + h;
    int cur = h & 1;
    // c loads issued BEFORE next stage -> older in vmcnt order (wait stays valid)
    float4 ccA = *(const float4*)&c_ws[(size_t)bh * T_DIM + tqA];
    float4 ccB = *(const float4*)&c_ws[(size_t)bh * T_DIM + tqB];
    // barrier 1: all waves done reading buf[cur^1] -> safe to overwrite
    __builtin_amdgcn_s_barrier();
    if (h + 1 < 16) {
      stage_qk(qh0 + (size_t)(h + 1) * hstride, kh0 + (size_t)(h + 1) * hstride,
               tbase, sbase, Qt[cur ^ 1], Kt[cur ^ 1], tid);
      asm volatile("s_waitcnt vmcnt(6)" ::: "memory");  // stage(h) retired
    } else {
      asm volatile("s_waitcnt vmcnt(0)" ::: "memory");
    }
    // barrier 2: every wave's stage(h) complete
    __builtin_amdgcn_s_barrier();
    __builtin_amdgcn_sched_barrier(0);
    const short* Qc = Qt[cur];
    const short* Kc = Kt[cur];

    bf16x8 qfA0 = *(const bf16x8*)&Qc[(tw + tp) * 64 + (g ^ sw) * 8];
    bf16x8 qfA1 = *(const bf16x8*)&Qc[(tw + tp) * 64 + ((g | 4) ^ sw) * 8];
    bf16x8 qfB0 = *(const bf16x8*)&Qc[(tw + 16 + tp) * 64 + (g ^ sw) * 8];
    bf16x8 qfB1 = *(const bf16x8*)&Qc[(tw + 16 + tp) * 64 + ((g | 4) ^ sw) * 8];
#pragma unroll
    for (int st = 0; st < 4; ++st) {
      int row = st * 16 + tp;
      bf16x8 kf0 = *(const bf16x8*)&Kc[row * 64 + (g ^ sw) * 8];
      bf16x8 kf1 = *(const bf16x8*)&Kc[row * 64 + ((g | 4) ^ sw) * 8];
      f32x4 zA = (f32x4){0.f, 0.f, 0.f, 0.f};
      zA = mfma_bf16(qfA0, kf0, zA);
      zA = mfma_bf16(qfA1, kf1, zA);
      f32x4 zB = (f32x4){0.f, 0.f, 0.f, 0.f};
      zB = mfma_bf16(qfB0, kf0, zB);
      zB = mfma_bf16(qfB1, kf1, zB);
      wsA[st][0] += exp2_hw(zA[0] + ccA.x);
      wsA[st][1] += exp2_hw(zA[1] + ccA.y);
      wsA[st][2] += exp2_hw(zA[2] + ccA.z);
      wsA[st][3] += exp2_hw(zA[3] + ccA.w);
      wsB[st][0] += exp2_hw(zB[0] + ccB.x);
      wsB[st][1] += exp2_hw(zB[1] + ccB.y);
      wsB[st][2] += exp2_hw(zB[2] + ccB.z);
      wsB[st][3] += exp2_hw(zB[3] + ccB.w);
    }
  }

#pragma unroll
  for (int st = 0; st < 4; st++)
#pragma unroll
    for (int r = 0; r < 4; r++) {
      wout[((size_t)b * T_DIM + tqA + r) * T_DIM + sbase + st * 16 + tp] =
          wsA[st][r] * 0.0625f;
      wout[((size_t)b * T_DIM + tqB + r) * T_DIM + sbase + st * 16 + tp] =
          wsB[st][r] * 0.0625f;
    }
}

// ---------------------------------------------------------------------------
// Launch
// ---------------------------------------------------------------------------
extern "C" void kernel_launch(void* const* d_in, const int* in_sizes, int n_in,
                              void* d_out, int out_size, void* d_ws, size_t ws_size,
                              hipStream_t stream) {
  const float* query = (const float*)d_in[0];
  const float* key = (const float*)d_in[1];
  const float* value = (const float*)d_in[2];
  const float* in_proj_w = (const float*)d_in[3];
  const float* in_proj_b = (const float*)d_in[4];
  const float* out_w = (const float*)d_in[5];
  const float* out_b = (const float*)d_in[6];
  // gate params d_in[7..12] are dead: top_k == out_features -> mask == all-ones.

  float* out = (float*)d_out;                 // attn_output: 4096*1024 f32
  float* wout = out + (size_t)M_ROWS * E_DIM; // attn_weights: 2*2048*2048 f32

  char* ws = (char*)d_ws;
  short* Wb = (short*)ws;                               // qkv + out weights bf16
  short* Xb = (short*)(ws + (8ull << 20));              // q,k,v inputs bf16
  short* q_s = (short*)(ws + (32ull << 20));
  short* k_s = (short*)(ws + (40ull << 20));
  short* vT = (short*)(ws + (48ull << 20));
  short* AO = (short*)(ws + (56ull << 20));
  float* c_ws = (float*)(ws + (64ull << 20));           // 256KB f32 stats

  // 1. convert inputs + weights to bf16 (single fused launch)
  cvt_all_kernel<<<16384, 256, 0, stream>>>(query, key, value, in_proj_w, out_w,
                                            Xb, Wb);

  // 2. q/k/v projections (batched over z)
  proj_gemm_kernel<<<dim3(8, 32, 3), 256, 0, stream>>>(
      Xb, Wb, in_proj_b, q_s, k_s, vT, nullptr, -1);

  // 3. flash attention (PV + stats)
  flash_fwd_kernel<<<dim3(16, 32), 256, 0, stream>>>(q_s, k_s, vT, AO, c_ws);

  // 4. attn_weights (head-averaged softmax)
  attn_weights_kernel<<<dim3(32, 16, 2), 256, 0, stream>>>(q_s, k_s, c_ws, wout);

  // 5. output projection -> d_out
  proj_gemm_kernel<<<dim3(8, 32, 1), 256, 0, stream>>>(
      AO, Wb, out_b, nullptr, nullptr, nullptr, out, 3);
}

// Round 15
// 176.029 us; speedup vs baseline: 1.0605x; 1.0605x over previous
//
#include <hip/hip_runtime.h>
#include <hip/hip_bf16.h>
#include <cstdint>
#include <cstddef>

// Problem constants
#define T_DIM 2048
#define B_DIM 2
#define E_DIM 1024
#define H_DIM 16
#define HD_DIM 64
#define M_ROWS 4096   // T*B
#define BH_DIM 32     // B*H

typedef __attribute__((ext_vector_type(8))) short bf16x8;
typedef __attribute__((ext_vector_type(4))) float f32x4;

__device__ __forceinline__ short f2bf(float x) {
  unsigned u = __float_as_uint(x);
  u += 0x7fffu + ((u >> 16) & 1u);
  return (short)(u >> 16);
}

__device__ __forceinline__ float exp2_hw(float x) {
  return __builtin_amdgcn_exp2f(x);  // v_exp_f32: D = 2^S0
}

__device__ __forceinline__ f32x4 mfma_bf16(bf16x8 a, bf16x8 b, f32x4 c) {
  return __builtin_amdgcn_mfma_f32_16x16x32_bf16(a, b, c, 0, 0, 0);
}

__device__ __forceinline__ unsigned cvt_pk_bf16(float lo, float hi) {
  unsigned r;
  asm volatile("v_cvt_pk_bf16_f32 %0, %1, %2" : "=v"(r) : "v"(lo), "v"(hi));
  return r;
}

__device__ __forceinline__ void gload_lds16(const void* g, void* l) {
  __builtin_amdgcn_global_load_lds(
      (const __attribute__((address_space(1))) void*)g,
      (__attribute__((address_space(3))) void*)l,
      16, 0, 0);
}

// ---------------------------------------------------------------------------
// Fused f32 -> bf16 conversion: one launch covers q/k/v/in_proj_w/out_w.
// ---------------------------------------------------------------------------
__global__ __launch_bounds__(256) void cvt_all_kernel(
    const float* __restrict__ q, const float* __restrict__ k,
    const float* __restrict__ v, const float* __restrict__ w_in,
    const float* __restrict__ w_out, short* __restrict__ Xb,
    short* __restrict__ Wb) {
  int bid = blockIdx.x;
  const float* src;
  short* dst;
  int base;
  if (bid < 4096) {
    src = q; dst = Xb; base = bid;
  } else if (bid < 8192) {
    src = k; dst = Xb + 4194304; base = bid - 4096;
  } else if (bid < 12288) {
    src = v; dst = Xb + 8388608; base = bid - 8192;
  } else if (bid < 15360) {
    src = w_in; dst = Wb; base = bid - 12288;
  } else {
    src = w_out; dst = Wb + 3145728; base = bid - 15360;
  }
  int i = base * 256 + threadIdx.x;
  float4 vv = ((const float4*)src)[i];
  short4 o;
  o.x = f2bf(vv.x); o.y = f2bf(vv.y); o.z = f2bf(vv.z); o.w = f2bf(vv.w);
  ((short4*)dst)[i] = o;
}

// ---------------------------------------------------------------------------
// Projection GEMM (R13-proven BK=32): C[row,col] = sum_k A[row,k]*W[col,k]+b.
// 128x128 tile, 256 threads (4 waves 2x2), global_load_lds staging.
// XCD-chunked tile swizzle (bijective on the 256-block x*y grid).
// mode 0: q (scaled log2e/8) / 1: k / 2: v (transposed) / 3: out (f32)
// ---------------------------------------------------------------------------
__global__ __launch_bounds__(256) void proj_gemm_kernel(
    const short* __restrict__ A0, const short* __restrict__ W0,
    const float* __restrict__ b0,
    short* __restrict__ q_s, short* __restrict__ k_s, short* __restrict__ vT,
    float* __restrict__ outf, int mode_in) {
  int mode = (mode_in < 0) ? (int)blockIdx.z : mode_in;
  const short* A = (mode_in < 0) ? A0 + (size_t)mode * (size_t)M_ROWS * 1024 : A0;
  const short* W = W0 + (size_t)mode * 1024 * 1024;
  const float* bias = (mode_in < 0) ? b0 + mode * 1024 : b0;

  __shared__ short As[128 * 32];
  __shared__ short Bs[128 * 32];

  int tid = threadIdx.x;
  int lane = tid & 63;
  int wave = tid >> 6;
  int wm = wave >> 1, wn = wave & 1;
  // XCD-chunked swizzle: HW dispatch id h -> logical tile l so each XCD
  // (h%8) gets 32 consecutive logical tiles (4 brow-panels x 8 bcols).
  int hwid = blockIdx.y * 8 + blockIdx.x;  // 0..255
  int l = (hwid & 7) * 32 + (hwid >> 3);   // bijective
  int brow = (l >> 3) * 128;
  int bcol = (l & 7) * 128;

  f32x4 acc[4][4];
#pragma unroll
  for (int i = 0; i < 4; i++)
#pragma unroll
    for (int j = 0; j < 4; j++) acc[i][j] = (f32x4){0.f, 0.f, 0.f, 0.f};

  for (int k0 = 0; k0 < 1024; k0 += 32) {
#pragma unroll
    for (int j = 0; j < 2; j++) {
      int chunk = wave * 2 + j;            // 0..7, 16 rows each
      int row = chunk * 16 + (lane >> 2);
      int col = (lane & 3) * 8;
      gload_lds16(A + (size_t)(brow + row) * 1024 + k0 + col, &As[chunk * 512]);
      gload_lds16(W + (size_t)(bcol + row) * 1024 + k0 + col, &Bs[chunk * 512]);
    }
    __syncthreads();

    bf16x8 af[4], bf_[4];
#pragma unroll
    for (int mi = 0; mi < 4; mi++)
      af[mi] = *(const bf16x8*)&As[(wm * 64 + mi * 16 + (lane & 15)) * 32 + (lane >> 4) * 8];
#pragma unroll
    for (int ni = 0; ni < 4; ni++)
      bf_[ni] = *(const bf16x8*)&Bs[(wn * 64 + ni * 16 + (lane & 15)) * 32 + (lane >> 4) * 8];
#pragma unroll
    for (int mi = 0; mi < 4; mi++)
#pragma unroll
      for (int ni = 0; ni < 4; ni++)
        acc[mi][ni] = mfma_bf16(af[mi], bf_[ni], acc[mi][ni]);
    __syncthreads();
  }

#pragma unroll
  for (int mi = 0; mi < 4; mi++) {
#pragma unroll
    for (int ni = 0; ni < 4; ni++) {
      int col = bcol + wn * 64 + ni * 16 + (lane & 15);
      float bv = bias[col];
      int row0 = brow + wm * 64 + mi * 16 + (lane >> 4) * 4;
#pragma unroll
      for (int r = 0; r < 4; r++) {
        int row = row0 + r;
        float val = acc[mi][ni][r] + bv;
        int t = row >> 1, b = row & 1;
        int h = col >> 6, hd = col & 63;
        if (mode == 0) {
          // 0.125 (1/sqrt(HD)) * log2(e): scores become log2-domain
          q_s[((size_t)((b << 4) + h) * T_DIM + t) * HD_DIM + hd] =
              f2bf(val * 0.1803368801f);
        } else if (mode == 1) {
          k_s[((size_t)((b << 4) + h) * T_DIM + t) * HD_DIM + hd] = f2bf(val);
        } else if (mode == 2) {
          vT[((size_t)((b << 4) + h) * HD_DIM + hd) * T_DIM + t] = f2bf(val);
        } else {
          outf[(size_t)row * 1024 + col] = val;
        }
      }
    }
  }
}

// ---------------------------------------------------------------------------
// Flash attention v5 + XCD-chunked block swizzle (proven, 59.1us; FETCH 12MB).
// Swapped QK^T, packed b64 P writes, 32 t/wave, counted-vmcnt two-barrier
// pipeline, exp2 domain. Writes AO (bf16) and c[bh][t] = -log2(l).
// ---------------------------------------------------------------------------
__device__ __forceinline__ void stage_kv(const short* kb, const short* vb, int s0,
                                         short* Ktb, short* Vtb, int tid) {
  int r0 = tid >> 3;                 // row 0..31 (issue 0) / +32 (issue 1)
  int sx = (tid & 7) ^ (r0 & 7);     // pre-swizzled source slot (16B units)
  gload_lds16(kb + (size_t)(s0 + r0) * 64 + sx * 8, Ktb + tid * 8);
  gload_lds16(kb + (size_t)(s0 + 32 + r0) * 64 + sx * 8, Ktb + 2048 + tid * 8);
  gload_lds16(vb + (size_t)r0 * T_DIM + s0 + sx * 8, Vtb + tid * 8);
  gload_lds16(vb + (size_t)(32 + r0) * T_DIM + s0 + sx * 8, Vtb + 2048 + tid * 8);
}

__global__ __launch_bounds__(256) void flash_fwd_kernel(
    const short* __restrict__ q_s, const short* __restrict__ k_s,
    const short* __restrict__ vT, short* __restrict__ AO,
    float* __restrict__ c_ws) {
  int tid = threadIdx.x;
  int lane = tid & 63;
  int wave = tid >> 6;
  // XCD-chunked swizzle: 512 blocks, XCD = hw%8 owns 64 logical blocks
  // = 4 complete bh groups of 16 t-blocks (bijective).
  int lin = blockIdx.y * 16 + blockIdx.x;  // 0..511
  int L = (lin & 7) * 64 + (lin >> 3);
  int bh = L >> 4;
  int t0w = (L & 15) * 128 + wave * 32;    // wave owns 32 t rows
  int tp = lane & 15;
  int g = lane >> 4;
  int sw = tp & 7;

  const short* qb = q_s + (size_t)bh * T_DIM * HD_DIM;
  const short* kb = k_s + (size_t)bh * T_DIM * HD_DIM;
  const short* vb = vT + (size_t)bh * HD_DIM * T_DIM;

  __shared__ short Kt[2][64 * 64];     // [s][hd], XOR-swizzled slots
  __shared__ short Vt[2][64 * 64];     // [hd][s], XOR-swizzled slots
  __shared__ short Pt[4][2][16 * 72];  // per-wave, per-half P; row stride 72

  // B-operand Q fragments for both 16-row halves
  bf16x8 qfA0 = *(const bf16x8*)&qb[(t0w + tp) * HD_DIM + g * 8];
  bf16x8 qfA1 = *(const bf16x8*)&qb[(t0w + tp) * HD_DIM + 32 + g * 8];
  bf16x8 qfB0 = *(const bf16x8*)&qb[(t0w + 16 + tp) * HD_DIM + g * 8];
  bf16x8 qfB1 = *(const bf16x8*)&qb[(t0w + 16 + tp) * HD_DIM + 32 + g * 8];

  f32x4 accA[4], accB[4];
#pragma unroll
  for (int i = 0; i < 4; i++) {
    accA[i] = (f32x4){0.f, 0.f, 0.f, 0.f};
    accB[i] = (f32x4){0.f, 0.f, 0.f, 0.f};
  }
  float lA = 0.f, lB = 0.f;

  short* PA = Pt[wave][0];
  short* PB = Pt[wave][1];

  stage_kv(kb, vb, 0, Kt[0], Vt[0], tid);

#pragma unroll 1
  for (int i = 0; i < 32; ++i) {
    int cur = i & 1;
    // barrier 1: all waves done READING buf[cur^1] (iter i-1) -> safe to overwrite
    __builtin_amdgcn_s_barrier();
    if (i + 1 < 32) {
      stage_kv(kb, vb, (i + 1) * 64, Kt[cur ^ 1], Vt[cur ^ 1], tid);
      asm volatile("s_waitcnt vmcnt(4)" ::: "memory");  // stage(i) retired
    } else {
      asm volatile("s_waitcnt vmcnt(0)" ::: "memory");  // tail: drain
    }
    // barrier 2: every wave's stage(i) complete -> buf[cur] readable
    __builtin_amdgcn_s_barrier();
    __builtin_amdgcn_sched_barrier(0);
    const short* Kc = Kt[cur];
    const short* Vc = Vt[cur];

    // QK^T (swapped: A=K rows s, B=Q rows t) + softmax-numerator + packed P
#pragma unroll
    for (int sn = 0; sn < 4; ++sn) {
      int row = sn * 16 + tp;
      bf16x8 kf0 = *(const bf16x8*)&Kc[row * 64 + (g ^ sw) * 8];
      bf16x8 kf1 = *(const bf16x8*)&Kc[row * 64 + ((g | 4) ^ sw) * 8];
      f32x4 zA = (f32x4){0.f, 0.f, 0.f, 0.f};
      zA = mfma_bf16(kf0, qfA0, zA);
      zA = mfma_bf16(kf1, qfA1, zA);
      f32x4 zB = (f32x4){0.f, 0.f, 0.f, 0.f};
      zB = mfma_bf16(kf0, qfB0, zB);
      zB = mfma_bf16(kf1, qfB1, zB);
      float a0 = exp2_hw(zA[0]), a1 = exp2_hw(zA[1]);
      float a2 = exp2_hw(zA[2]), a3 = exp2_hw(zA[3]);
      float b0 = exp2_hw(zB[0]), b1 = exp2_hw(zB[1]);
      float b2 = exp2_hw(zB[2]), b3 = exp2_hw(zB[3]);
      lA += (a0 + a1) + (a2 + a3);
      lB += (b0 + b1) + (b2 + b3);
      uint2 wa, wb;
      wa.x = cvt_pk_bf16(a0, a1); wa.y = cvt_pk_bf16(a2, a3);
      wb.x = cvt_pk_bf16(b0, b1); wb.y = cvt_pk_bf16(b2, b3);
      *(uint2*)&PA[tp * 72 + sn * 16 + g * 4] = wa;  // s = sn*16 + g*4 + 0..3
      *(uint2*)&PB[tp * 72 + sn * 16 + g * 4] = wb;
    }

    // PV: A = P rows t, B = V^T rows hd (V fragments shared across halves)
#pragma unroll
    for (int c32 = 0; c32 < 2; ++c32) {
      bf16x8 pfA = *(const bf16x8*)&PA[tp * 72 + c32 * 32 + g * 8];
      bf16x8 pfB = *(const bf16x8*)&PB[tp * 72 + c32 * 32 + g * 8];
#pragma unroll
      for (int hdt = 0; hdt < 4; ++hdt) {
        bf16x8 vf = *(const bf16x8*)&Vc[(hdt * 16 + tp) * 64 + ((c32 * 4 + g) ^ sw) * 8];
        accA[hdt] = mfma_bf16(pfA, vf, accA[hdt]);
        accB[hdt] = mfma_bf16(pfB, vf, accB[hdt]);
      }
    }
  }

  // epilogue: reduce l per t-row (lane's l is for t-row tp of its half)
  lA += __shfl_xor(lA, 16); lA += __shfl_xor(lA, 32);
  lB += __shfl_xor(lB, 16); lB += __shfl_xor(lB, 32);
  float liA[4], liB[4];
#pragma unroll
  for (int r = 0; r < 4; r++) {
    liA[r] = 1.0f / __shfl(lA, g * 4 + r);
    liB[r] = 1.0f / __shfl(lB, g * 4 + r);
  }
  int b = bh >> 4, h = bh & 15;
#pragma unroll
  for (int hdt = 0; hdt < 4; hdt++) {
#pragma unroll
    for (int r = 0; r < 4; r++) {
      int tA = t0w + g * 4 + r;
      int tB = t0w + 16 + g * 4 + r;
      AO[(size_t)(tA * 2 + b) * E_DIM + h * 64 + hdt * 16 + tp] =
          f2bf(accA[hdt][r] * liA[r]);
      AO[(size_t)(tB * 2 + b) * E_DIM + h * 64 + hdt * 16 + tp] =
          f2bf(accB[hdt][r] * liB[r]);
    }
  }
  if (lane < 16) {
    c_ws[bh * T_DIM + t0w + tp] = -__log2f(lA);
    c_ws[bh * T_DIM + t0w + 16 + tp] = -__log2f(lB);
  }
}

// ---------------------------------------------------------------------------
// attn_weights v3 + XCD-chunked swizzle: out[b,t,s] = (1/H) * sum_h
// exp2(score[bh,t,s] + c[bh,t]). Block 128t x 64s, 4 waves x 32 t-rows;
// per head stage Q(128x64)+K(64x64) (dbuf, XOR-swizzled source),
// counted-vmcnt two-barrier pipeline. Each XCD owns 128 contiguous logical
// blocks (one batch, 4 tbase panels, all sbase) -> Q/K panels stay in its L2.
// ---------------------------------------------------------------------------
__device__ __forceinline__ void stage_qk(const short* qh, const short* kh,
                                         int tbase, int sbase,
                                         short* Qb, short* Kb, int tid) {
  int r0 = tid >> 3;                 // row 0..31
  int sx = (tid & 7) ^ (r0 & 7);     // pre-swizzled source slot (16B units)
#pragma unroll
  for (int c = 0; c < 4; ++c)        // Q: 128 rows, 4 chunks of 32
    gload_lds16(qh + (size_t)(tbase + c * 32 + r0) * 64 + sx * 8,
                Qb + c * 2048 + tid * 8);
  gload_lds16(kh + (size_t)(sbase + r0) * 64 + sx * 8, Kb + tid * 8);
  gload_lds16(kh + (size_t)(sbase + 32 + r0) * 64 + sx * 8, Kb + 2048 + tid * 8);
}

__global__ __launch_bounds__(256) void attn_weights_kernel(
    const short* __restrict__ q_s, const short* __restrict__ k_s,
    const float* __restrict__ c_ws, float* __restrict__ wout) {
  int tid = threadIdx.x;
  int lane = tid & 63;
  int wave = tid >> 6;
  // XCD-chunked swizzle over the 1024-block grid (bijective):
  // lin = z*512 + y*32 + x (x fastest in dispatch); XCD = lin%8 gets
  // L in [xcd*128, xcd*128+128) = one b, 4 tbase panels, all 32 sbase.
  int lin = blockIdx.z * 512 + blockIdx.y * 32 + blockIdx.x;
  int L = (lin & 7) * 128 + (lin >> 3);
  int b = L >> 9;
  int tbase = ((L >> 5) & 15) * 128;
  int sbase = (L & 31) * 64;
  int tp = lane & 15;
  int g = lane >> 4;
  int tw = wave * 32;                 // wave's local t-row base (32 rows)
  int tqA = tbase + tw + g * 4;       // accumulator t bases
  int tqB = tqA + 16;
  int sw = tp & 7;

  __shared__ short Qt[2][128 * 64];
  __shared__ short Kt[2][64 * 64];

  float wsA[4][4], wsB[4][4];
#pragma unroll
  for (int st = 0; st < 4; st++)
#pragma unroll
    for (int r = 0; r < 4; r++) { wsA[st][r] = 0.f; wsB[st][r] = 0.f; }

  const size_t hstride = (size_t)T_DIM * HD_DIM;
  const short* qh0 = q_s + (size_t)(b * 16) * hstride;
  const short* kh0 = k_s + (size_t)(b * 16) * hstride;

  stage_qk(qh0, kh0, tbase, sbase, Qt[0], Kt[0], tid);

#pragma unroll 1
  for (int h = 0; h < 16; ++h) {
    int bh = b * 16 + h;
    int cur = h & 1;
    // c loads issued BEFORE next stage -> older in vmcnt order (wait stays valid)
    float4 ccA = *(const float4*)&c_ws[(size_t)bh * T_DIM + tqA];
    float4 ccB = *(const float4*)&c_ws[(size_t)bh * T_DIM + tqB];
    // barrier 1: all waves done reading buf[cur^1] -> safe to overwrite
    __builtin_amdgcn_s_barrier();
    if (h + 1 < 16) {
      stage_qk(qh0 + (size_t)(h + 1) * hstride, kh0 + (size_t)(h + 1) * hstride,
               tbase, sbase, Qt[cur ^ 1], Kt[cur ^ 1], tid);
      asm volatile("s_waitcnt vmcnt(6)" ::: "memory");  // stage(h) retired
    } else {
      asm volatile("s_waitcnt vmcnt(0)" ::: "memory");
    }
    // barrier 2: every wave's stage(h) complete
    __builtin_amdgcn_s_barrier();
    __builtin_amdgcn_sched_barrier(0);
    const short* Qc = Qt[cur];
    const short* Kc = Kt[cur];

    bf16x8 qfA0 = *(const bf16x8*)&Qc[(tw + tp) * 64 + (g ^ sw) * 8];
    bf16x8 qfA1 = *(const bf16x8*)&Qc[(tw + tp) * 64 + ((g | 4) ^ sw) * 8];
    bf16x8 qfB0 = *(const bf16x8*)&Qc[(tw + 16 + tp) * 64 + (g ^ sw) * 8];
    bf16x8 qfB1 = *(const bf16x8*)&Qc[(tw + 16 + tp) * 64 + ((g | 4) ^ sw) * 8];
#pragma unroll
    for (int st = 0; st < 4; ++st) {
      int row = st * 16 + tp;
      bf16x8 kf0 = *(const bf16x8*)&Kc[row * 64 + (g ^ sw) * 8];
      bf16x8 kf1 = *(const bf16x8*)&Kc[row * 64 + ((g | 4) ^ sw) * 8];
      f32x4 zA = (f32x4){0.f, 0.f, 0.f, 0.f};
      zA = mfma_bf16(qfA0, kf0, zA);
      zA = mfma_bf16(qfA1, kf1, zA);
      f32x4 zB = (f32x4){0.f, 0.f, 0.f, 0.f};
      zB = mfma_bf16(qfB0, kf0, zB);
      zB = mfma_bf16(qfB1, kf1, zB);
      wsA[st][0] += exp2_hw(zA[0] + ccA.x);
      wsA[st][1] += exp2_hw(zA[1] + ccA.y);
      wsA[st][2] += exp2_hw(zA[2] + ccA.z);
      wsA[st][3] += exp2_hw(zA[3] + ccA.w);
      wsB[st][0] += exp2_hw(zB[0] + ccB.x);
      wsB[st][1] += exp2_hw(zB[1] + ccB.y);
      wsB[st][2] += exp2_hw(zB[2] + ccB.z);
      wsB[st][3] += exp2_hw(zB[3] + ccB.w);
    }
  }

#pragma unroll
  for (int st = 0; st < 4; st++)
#pragma unroll
    for (int r = 0; r < 4; r++) {
      wout[((size_t)b * T_DIM + tqA + r) * T_DIM + sbase + st * 16 + tp] =
          wsA[st][r] * 0.0625f;
      wout[((size_t)b * T_DIM + tqB + r) * T_DIM + sbase + st * 16 + tp] =
          wsB[st][r] * 0.0625f;
    }
}

// ---------------------------------------------------------------------------
// Launch
// ---------------------------------------------------------------------------
extern "C" void kernel_launch(void* const* d_in, const int* in_sizes, int n_in,
                              void* d_out, int out_size, void* d_ws, size_t ws_size,
                              hipStream_t stream) {
  const float* query = (const float*)d_in[0];
  const float* key = (const float*)d_in[1];
  const float* value = (const float*)d_in[2];
  const float* in_proj_w = (const float*)d_in[3];
  const float* in_proj_b = (const float*)d_in[4];
  const float* out_w = (const float*)d_in[5];
  const float* out_b = (const float*)d_in[6];
  // gate params d_in[7..12] are dead: top_k == out_features -> mask == all-ones.

  float* out = (float*)d_out;                 // attn_output: 4096*1024 f32
  float* wout = out + (size_t)M_ROWS * E_DIM; // attn_weights: 2*2048*2048 f32

  char* ws = (char*)d_ws;
  short* Wb = (short*)ws;                               // qkv + out weights bf16
  short* Xb = (short*)(ws + (8ull << 20));              // q,k,v inputs bf16
  short* q_s = (short*)(ws + (32ull << 20));
  short* k_s = (short*)(ws + (40ull << 20));
  short* vT = (short*)(ws + (48ull << 20));
  short* AO = (short*)(ws + (56ull << 20));
  float* c_ws = (float*)(ws + (64ull << 20));           // 256KB f32 stats

  // 1. convert inputs + weights to bf16 (single fused launch)
  cvt_all_kernel<<<16384, 256, 0, stream>>>(query, key, value, in_proj_w, out_w,
                                            Xb, Wb);

  // 2. q/k/v projections (batched over z)
  proj_gemm_kernel<<<dim3(8, 32, 3), 256, 0, stream>>>(
      Xb, Wb, in_proj_b, q_s, k_s, vT, nullptr, -1);

  // 3. flash attention (PV + stats)
  flash_fwd_kernel<<<dim3(16, 32), 256, 0, stream>>>(q_s, k_s, vT, AO, c_ws);

  // 4. attn_weights (head-averaged softmax)
  attn_weights_kernel<<<dim3(32, 16, 2), 256, 0, stream>>>(q_s, k_s, c_ws, wout);

  // 5. output projection -> d_out
  proj_gemm_kernel<<<dim3(8, 32, 1), 256, 0, stream>>>(
      AO, Wb, out_b, nullptr, nullptr, nullptr, out, 3);
}